// Round 4
// baseline (485.832 us; speedup 1.0000x reference)
//
#include <hip/hip_runtime.h>
#include <hip/hip_bf16.h>

// Reference returns (input0, input1) unchanged — the vmap'd scan is dead code.
// d_out = concat(input0.flat, input1.flat), each 2048*65536 f32 elements.
// Pure memory-bound copy: 1 GiB in + 1 GiB out => ~341 us at 6.3 TB/s.
//
// R1: 452 us (4.74 TB/s) — two sequential grid-stride loops, 4 streams/thread.
// R3: 454 us — nt flag + fused loop NEUTRAL => not cache-, not MLP-limited.
// R4: split the GRID, not the loop: blocks [0,2048) copy a->out, blocks
//     [2048,4096) copy b->out+n4. Each wave = 1 read + 1 write stream
//     (the m13 6.29 TB/s configuration). Unroll x4, loads batched before
//     stores. 16 outer iters exactly, no tail.

typedef float f32x4 __attribute__((ext_vector_type(4)));

__global__ __launch_bounds__(256) void concat_copy_kernel(
    const f32x4* __restrict__ a,
    const f32x4* __restrict__ b,
    f32x4* __restrict__ out,
    long n4,          // f32x4 count per input
    int half_grid) {  // blocks per half
    const f32x4* __restrict__ src;
    f32x4* __restrict__ dst;
    long bid = blockIdx.x;
    if (bid < half_grid) {
        src = a;
        dst = out;
    } else {
        src = b;
        dst = out + n4;
        bid -= half_grid;
    }
    long tid = bid * blockDim.x + threadIdx.x;
    long stride = (long)half_grid * blockDim.x;   // 524288 threads per half
    long stride4 = 4 * stride;
    for (long k = tid; k < n4; k += stride4) {
        f32x4 v0 = __builtin_nontemporal_load(&src[k]);
        f32x4 v1 = __builtin_nontemporal_load(&src[k + stride]);
        f32x4 v2 = __builtin_nontemporal_load(&src[k + 2 * stride]);
        f32x4 v3 = __builtin_nontemporal_load(&src[k + 3 * stride]);
        __builtin_nontemporal_store(v0, &dst[k]);
        __builtin_nontemporal_store(v1, &dst[k + stride]);
        __builtin_nontemporal_store(v2, &dst[k + 2 * stride]);
        __builtin_nontemporal_store(v3, &dst[k + 3 * stride]);
    }
}

extern "C" void kernel_launch(void* const* d_in, const int* in_sizes, int n_in,
                              void* d_out, int out_size, void* d_ws, size_t ws_size,
                              hipStream_t stream) {
    const f32x4* in0 = (const f32x4*)d_in[0];
    const f32x4* in1 = (const f32x4*)d_in[1];
    f32x4* out = (f32x4*)d_out;

    long n = (long)in_sizes[0];       // 2048*65536 = 134217728, divisible by 4
    long n4 = n / 4;                  // 33554432 f32x4 per input

    const int block = 256;
    const int half_grid = 2048;       // 8 blocks/CU per half over 256 CUs
    const int grid = 2 * half_grid;

    concat_copy_kernel<<<grid, block, 0, stream>>>(in0, in1, out, n4, half_grid);
}

// Round 5
// 365.552 us; speedup vs baseline: 1.3290x; 1.3290x over previous
//
#include <hip/hip_runtime.h>
#include <hip/hip_bf16.h>

// Reference returns (input0, input1) unchanged — the vmap'd scan is dead code.
// d_out = concat(input0.flat, input1.flat), each 2048*65536 f32 elements.
// Pure memory-bound copy: 1 GiB in + 1 GiB out => ~341 us at 6.3 TB/s.
//
// R1: 452 us (4.74 TB/s) — 2048-block grid-stride, cached.
// R3: 454 us — nt + fused loop NEUTRAL (not cache-, not MLP-limited).
// R4: 486 us — 4096-block grid-split REGRESSED (2-pass block sched).
// R5: rocclr-shape copy — massive grid, one-shot 32B/thread, 8KiB/block,
//     contiguous block->address map (the fillBuffer/m13 pattern that hits
//     6.3-6.5 TB/s on this box). Block range split: [0,half) a->out,
//     [half,2*half) b->out+n4. No loops, no tail (sizes divide exactly).

typedef float f32x4 __attribute__((ext_vector_type(4)));

__global__ __launch_bounds__(256) void concat_copy_kernel(
    const f32x4* __restrict__ a,
    const f32x4* __restrict__ b,
    f32x4* __restrict__ out,
    long n4,         // f32x4 count per input (33554432)
    int half_grid) { // blocks per half
    long bid = blockIdx.x;
    const f32x4* __restrict__ src = a;
    f32x4* __restrict__ dst = out;
    if (bid >= half_grid) {
        src = b;
        dst = out + n4;
        bid -= half_grid;
    }
    // 2 x float4 per thread, contiguous per block: block owns 512 f32x4.
    long base = bid * (long)(2 * 256) + threadIdx.x;
    f32x4 v0 = __builtin_nontemporal_load(&src[base]);
    f32x4 v1 = __builtin_nontemporal_load(&src[base + 256]);
    __builtin_nontemporal_store(v0, &dst[base]);
    __builtin_nontemporal_store(v1, &dst[base + 256]);
}

extern "C" void kernel_launch(void* const* d_in, const int* in_sizes, int n_in,
                              void* d_out, int out_size, void* d_ws, size_t ws_size,
                              hipStream_t stream) {
    const f32x4* in0 = (const f32x4*)d_in[0];
    const f32x4* in1 = (const f32x4*)d_in[1];
    f32x4* out = (f32x4*)d_out;

    long n = (long)in_sizes[0];       // 2048*65536 = 134217728
    long n4 = n / 4;                  // 33554432 f32x4 per input

    const int block = 256;
    // 512 f32x4 per block -> 65536 blocks per half, no remainder.
    const int half_grid = (int)(n4 / 512);
    const int grid = 2 * half_grid;   // 131072 blocks

    concat_copy_kernel<<<grid, block, 0, stream>>>(in0, in1, out, n4, half_grid);
}

// Round 6
// 363.025 us; speedup vs baseline: 1.3383x; 1.0070x over previous
//
#include <hip/hip_runtime.h>
#include <hip/hip_bf16.h>

// Reference returns (input0, input1) unchanged — the vmap'd scan is dead code.
// d_out = concat(input0.flat, input1.flat), each 2048*65536 f32 elements.
// Pure memory-bound copy: 1 GiB in + 1 GiB out => ~341 us at 6.3 TB/s.
//
// R1: 452 us (4.74 TB/s) — 2048-block grid-stride, cached.
// R3: 454 us — nt + fused loop NEUTRAL (not cache-, not MLP-limited).
// R4: 486 us — 4096-block grid-split REGRESSED (2-pass block sched).
// R5: 365 us (5.87 TB/s, 93% of copy ceiling) — rocclr-shape WIN: massive
//     grid, one-shot 32B/thread, 8KiB/block, contiguous block->addr sweep.
// R6: same shape, 64B/thread (4xfloat4, 16KiB/block, 65536 blocks): 4 loads
//     in flight before stores, half the block-sched churn.

typedef float f32x4 __attribute__((ext_vector_type(4)));

__global__ __launch_bounds__(256) void concat_copy_kernel(
    const f32x4* __restrict__ a,
    const f32x4* __restrict__ b,
    f32x4* __restrict__ out,
    long n4,         // f32x4 count per input (33554432)
    int half_grid) { // blocks per half
    long bid = blockIdx.x;
    const f32x4* __restrict__ src = a;
    f32x4* __restrict__ dst = out;
    if (bid >= half_grid) {
        src = b;
        dst = out + n4;
        bid -= half_grid;
    }
    // 4 x float4 per thread, contiguous per block: block owns 1024 f32x4.
    long base = bid * (long)(4 * 256) + threadIdx.x;
    f32x4 v0 = __builtin_nontemporal_load(&src[base]);
    f32x4 v1 = __builtin_nontemporal_load(&src[base + 256]);
    f32x4 v2 = __builtin_nontemporal_load(&src[base + 512]);
    f32x4 v3 = __builtin_nontemporal_load(&src[base + 768]);
    __builtin_nontemporal_store(v0, &dst[base]);
    __builtin_nontemporal_store(v1, &dst[base + 256]);
    __builtin_nontemporal_store(v2, &dst[base + 512]);
    __builtin_nontemporal_store(v3, &dst[base + 768]);
}

extern "C" void kernel_launch(void* const* d_in, const int* in_sizes, int n_in,
                              void* d_out, int out_size, void* d_ws, size_t ws_size,
                              hipStream_t stream) {
    const f32x4* in0 = (const f32x4*)d_in[0];
    const f32x4* in1 = (const f32x4*)d_in[1];
    f32x4* out = (f32x4*)d_out;

    long n = (long)in_sizes[0];       // 2048*65536 = 134217728
    long n4 = n / 4;                  // 33554432 f32x4 per input

    const int block = 256;
    // 1024 f32x4 per block -> 32768 blocks per half, no remainder.
    const int half_grid = (int)(n4 / 1024);
    const int grid = 2 * half_grid;   // 65536 blocks

    concat_copy_kernel<<<grid, block, 0, stream>>>(in0, in1, out, n4, half_grid);
}